// Round 4
// baseline (642.743 us; speedup 1.0000x reference)
//
#include <hip/hip_runtime.h>
#include <math.h>

#define BATCH 32768
#define NSP 26
#define NDN 13
#define VOC 10000
#define EDIM 64
#define NLAY 3
#define HID1 256
#define HID2 128
#define DIN 1677          // 13 + 26*64
#define XW 39             // NSP + NDN
#define KC1 53            // GEMM1 K-chunks of 32 (K padded 1677 -> 1696)

typedef short short8 __attribute__((ext_vector_type(8)));
typedef short short4v __attribute__((ext_vector_type(4)));
typedef float float4v __attribute__((ext_vector_type(4)));

__device__ __forceinline__ unsigned short f2b(float f) {
    unsigned u = __builtin_bit_cast(unsigned, f);
    u += 0x7FFFu + ((u >> 16) & 1u);          // RNE
    return (unsigned short)(u >> 16);
}
__device__ __forceinline__ float b2f(unsigned short h) {
    unsigned u = ((unsigned)h) << 16;
    return __builtin_bit_cast(float, u);
}
// pack two f32 -> two bf16 (RNE) in one u32:  [hi | lo]
__device__ __forceinline__ unsigned pk2(float lo, float hi) {
    unsigned ul = __builtin_bit_cast(unsigned, lo);
    unsigned uh = __builtin_bit_cast(unsigned, hi);
    ul += 0x7FFFu + ((ul >> 16) & 1u);
    uh += 0x7FFFu + ((uh >> 16) & 1u);
    return (uh & 0xFFFF0000u) | (ul >> 16);
}
// store 4 C-regs (consecutive dest elements) as one ds_write_b64
__device__ __forceinline__ void st4(unsigned short* p, float4v v) {
    uint2 u;
    u.x = pk2(v[0], v[1]);
    u.y = pk2(v[2], v[3]);
    *(uint2*)p = u;
}

// ---------------------------------------------------------------------------
// K0: pack all weights into MFMA fragment order (bf16).  (unchanged — the
// B-frag layout of W is identical to the A-frag layout of W^T, so the same
// buffer serves both roles in k_interact.)
//  bid <  192 : Wq/Wk/Wv/Wres -> pW  [l][m][nt4][kt2][lane][j8]
//  192..1887  : W1            -> pW1 [kc53][nt16][lane][j8]   (k>=1677 -> 0)
//  1888..2015 : W2            -> pW2 [kc8][nt8][lane][j8]
// fragment element = W[k = kc*32 + (lane>>4)*8 + j][n = nt*16 + (lane&15)]
// ---------------------------------------------------------------------------
__global__ void k_pack(const float* __restrict__ Wq, const float* __restrict__ Wk,
                       const float* __restrict__ Wv, const float* __restrict__ Wr,
                       const float* __restrict__ W1, const float* __restrict__ W2,
                       unsigned short* __restrict__ pW,
                       unsigned short* __restrict__ pW1,
                       unsigned short* __restrict__ pW2) {
    int bid = blockIdx.x;
    if (bid < 192) {
        int tid = bid * 256 + threadIdx.x;   // 49152 total
        int j    = tid & 7;
        int lane = (tid >> 3) & 63;
        int kt   = (tid >> 9) & 1;
        int nt   = (tid >> 10) & 3;
        int m    = (tid >> 12) & 3;
        int l    = tid >> 14;
        const float* W = (m == 0) ? Wq : (m == 1) ? Wk : (m == 2) ? Wv : Wr;
        int k = kt * 32 + ((lane >> 4) << 3) + j;
        int n = nt * 16 + (lane & 15);
        pW[tid] = f2b(W[l * EDIM * EDIM + k * EDIM + n]);
    } else if (bid < 1888) {
        int tid = (bid - 192) * 256 + threadIdx.x;   // 434176 total
        int j    = tid & 7;
        int lane = (tid >> 3) & 63;
        int nt   = (tid >> 9) & 15;
        int kc   = tid >> 13;
        int k = kc * 32 + ((lane >> 4) << 3) + j;
        int n = nt * 16 + (lane & 15);
        pW1[tid] = (k < DIN) ? f2b(W1[(long)k * HID1 + n]) : (unsigned short)0;
    } else {
        int tid = (bid - 1888) * 256 + threadIdx.x;  // 32768 total
        int j    = tid & 7;
        int lane = (tid >> 3) & 63;
        int nt   = (tid >> 9) & 7;
        int kc   = tid >> 12;
        int k = kc * 32 + ((lane >> 4) << 3) + j;
        int n = nt * 16 + (lane & 15);
        pW2[tid] = f2b(W2[(long)k * HID2 + n]);
    }
}

// ---------------------------------------------------------------------------
// K1: logit0[b] = relu(X[b,:] @ lin_W + lin_b)
// ---------------------------------------------------------------------------
__global__ void k_lin(const float* __restrict__ X, const float* __restrict__ lw,
                      const float* __restrict__ lb, float* __restrict__ logit0) {
    int b = blockIdx.x * 256 + threadIdx.x;
    float s = lb[0];
    const float* xr = X + (long)b * XW;
#pragma unroll
    for (int i = 0; i < XW; i++) s = fmaf(xr[i], lw[i], s);
    logit0[b] = fmaxf(s, 0.f);
}

// ---------------------------------------------------------------------------
// K2: fused 3-layer AutoInt interaction, MFMA bf16, TRANSPOSED products.
// One wave = one sample.  All LDS stores are packed ds_write_b64 because
// every product is computed so its C-layout regs (row=quad*4+reg) are 4
// consecutive elements of the destination row:
//   Q^T = Wq^T att^T  -> qb[q][d]    (C[d][q]: lane q, regs d consecutive)
//   K^T = Wk^T att^T  -> kb[key][d]
//   V   = att Wv      -> vtb[d][key] (C[q][d]: lane d, regs q=key consecutive)
//   R^T = Wr^T att^T  -> regs (C[d][q], matches O^T epilogue layout)
//   S^T = K Q^T       -> P[h][q][key]
//   O^T = V^T P^T     -> att[q][d]
// pW's B-frag-of-W layout == A-frag-of-W^T layout, so no repack needed.
// ---------------------------------------------------------------------------
__global__ __launch_bounds__(64) void k_interact(
    const int* __restrict__ sidx, const float* __restrict__ emb,
    const unsigned short* __restrict__ pW, const float* __restrict__ outW,
    float* __restrict__ p1)
{
    __shared__ __align__(16) unsigned short smem[32*72*3 + 64*40];
    unsigned short* att = smem;            // [32 q][72]  row-major [q][e]
    unsigned short* qb  = smem + 32*72;    // [32 q][72]  row-major [q][d]
    unsigned short* kb  = smem + 32*72*2;  // [32 key][72] row-major [key][d]
    unsigned short* vtb = smem + 32*72*3;  // [64 d][40 key]
    unsigned short* P   = qb;              // [2 h][32 q][40 key], spans qb+kb

    const int lane = threadIdx.x;
    const int b    = blockIdx.x;
    const int quad = lane >> 4;
    const int c16  = lane & 15;
    const float4v zero4 = {0.f, 0.f, 0.f, 0.f};

    // gather embeddings -> att (bf16), coalesced over lane=e
#pragma unroll
    for (int f = 0; f < NSP; f++) {
        int idx = sidx[b * NSP + f];
        att[f * 72 + lane] = f2b(emb[((long)(f * VOC + idx)) * EDIM + lane]);
    }
#pragma unroll
    for (int r = NSP; r < 32; r++) att[r * 72 + lane] = 0;   // zero pad rows
    __syncthreads();

    for (int l = 0; l < NLAY; l++) {
        // att fragments: serve as B-operand (att^T) for Q^T/K^T/R^T and as
        // A-operand (att) for V — identical register data for both roles.
        short8 Fatt[2][2];
#pragma unroll
        for (int qt = 0; qt < 2; qt++)
#pragma unroll
            for (int kt = 0; kt < 2; kt++)
                Fatt[qt][kt] = *(const short8*)&att[(qt*16 + c16)*72 + kt*32 + quad*8];

        const unsigned short* wl = pW + l * 16384;
        float4v Rf[4][2];            // R^T tiles: [d-tile][q-tile]

        // ---- projections: m = 0:Q^T 1:K^T 2:V 3:R^T ----
#pragma unroll
        for (int m = 0; m < 4; m++) {
            short8 Wf[4][2];
#pragma unroll
            for (int nt = 0; nt < 4; nt++)
#pragma unroll
                for (int kt = 0; kt < 2; kt++)
                    Wf[nt][kt] = *(const short8*)&wl[(m*8 + nt*2 + kt)*512 + lane*8];

            if (m == 0 || m == 1) {
                unsigned short* dst = (m == 0) ? qb : kb;
#pragma unroll
                for (int dt = 0; dt < 4; dt++)
#pragma unroll
                    for (int qt = 0; qt < 2; qt++) {
                        float4v acc = __builtin_amdgcn_mfma_f32_16x16x32_bf16(
                            Wf[dt][0], Fatt[qt][0], zero4, 0, 0, 0);
                        acc = __builtin_amdgcn_mfma_f32_16x16x32_bf16(
                            Wf[dt][1], Fatt[qt][1], acc, 0, 0, 0);
                        st4(&dst[(qt*16 + c16)*72 + dt*16 + quad*4], acc);
                    }
            } else if (m == 2) {
#pragma unroll
                for (int qt = 0; qt < 2; qt++)
#pragma unroll
                    for (int dt = 0; dt < 4; dt++) {
                        float4v acc = __builtin_amdgcn_mfma_f32_16x16x32_bf16(
                            Fatt[qt][0], Wf[dt][0], zero4, 0, 0, 0);
                        acc = __builtin_amdgcn_mfma_f32_16x16x32_bf16(
                            Fatt[qt][1], Wf[dt][1], acc, 0, 0, 0);
                        st4(&vtb[(dt*16 + c16)*40 + qt*16 + quad*4], acc);
                    }
            } else {
#pragma unroll
                for (int dt = 0; dt < 4; dt++)
#pragma unroll
                    for (int qt = 0; qt < 2; qt++) {
                        float4v acc = __builtin_amdgcn_mfma_f32_16x16x32_bf16(
                            Wf[dt][0], Fatt[qt][0], zero4, 0, 0, 0);
                        Rf[dt][qt] = __builtin_amdgcn_mfma_f32_16x16x32_bf16(
                            Wf[dt][1], Fatt[qt][1], acc, 0, 0, 0);
                    }
            }
        }
        __syncthreads();

        // ---- S^T = K·Q^T per head (k = d, 32 per head = 1 MFMA depth) ----
        short8 Ka[2][2], Qb[2][2];
#pragma unroll
        for (int h = 0; h < 2; h++)
#pragma unroll
            for (int i = 0; i < 2; i++) {
                Ka[h][i] = *(const short8*)&kb[(i*16 + c16)*72 + h*32 + quad*8];
                Qb[h][i] = *(const short8*)&qb[(i*16 + c16)*72 + h*32 + quad*8];
            }
        float4v S[2][2][2];
#pragma unroll
        for (int h = 0; h < 2; h++)
#pragma unroll
            for (int mk = 0; mk < 2; mk++)
#pragma unroll
                for (int nq = 0; nq < 2; nq++)
                    S[h][mk][nq] = __builtin_amdgcn_mfma_f32_16x16x32_bf16(
                        Ka[h][mk], Qb[h][nq], zero4, 0, 0, 0);
        __syncthreads();
        // C[key][q]: lane q=c16, regs = 4 consecutive keys -> b64 into P[h][q][key]
#pragma unroll
        for (int h = 0; h < 2; h++)
#pragma unroll
            for (int mk = 0; mk < 2; mk++)
#pragma unroll
                for (int nq = 0; nq < 2; nq++)
                    st4(&P[h*1280 + (nq*16 + c16)*40 + mk*16 + quad*4], S[h][mk][nq]);
        __syncthreads();

        // ---- row softmax: lane -> (h, q), 52 active lanes ----
        if (lane < 2 * NSP) {
            int h = lane / NSP, q = lane % NSP;
            unsigned short* row = &P[h*1280 + q*40];
            short8 r0 = *(const short8*)&row[0];
            short8 r1 = *(const short8*)&row[8];
            short8 r2 = *(const short8*)&row[16];
            short8 r3 = *(const short8*)&row[24];
            float v[26];
#pragma unroll
            for (int j = 0; j < 8; j++)  v[j]      = b2f((unsigned short)r0[j]);
#pragma unroll
            for (int j = 0; j < 8; j++)  v[8 + j]  = b2f((unsigned short)r1[j]);
#pragma unroll
            for (int j = 0; j < 8; j++)  v[16 + j] = b2f((unsigned short)r2[j]);
            v[24] = b2f((unsigned short)r3[0]);
            v[25] = b2f((unsigned short)r3[1]);
            float mx = v[0];
#pragma unroll
            for (int j = 1; j < 26; j++) mx = fmaxf(mx, v[j]);
            float sum = 0.f;
#pragma unroll
            for (int j = 0; j < 26; j++) { v[j] = __expf(v[j] - mx); sum += v[j]; }
            float inv = 1.f / sum;
            short8 w0, w1, w2, w3;
#pragma unroll
            for (int j = 0; j < 8; j++)  w0[j] = (short)f2b(v[j] * inv);
#pragma unroll
            for (int j = 0; j < 8; j++)  w1[j] = (short)f2b(v[8 + j] * inv);
#pragma unroll
            for (int j = 0; j < 8; j++)  w2[j] = (short)f2b(v[16 + j] * inv);
            w3[0] = (short)f2b(v[24] * inv);
            w3[1] = (short)f2b(v[25] * inv);
#pragma unroll
            for (int j = 2; j < 8; j++)  w3[j] = 0;     // pad keys 26..31 -> 0
            *(short8*)&row[0]  = w0;
            *(short8*)&row[8]  = w1;
            *(short8*)&row[16] = w2;
            *(short8*)&row[24] = w3;
        }
        __syncthreads();

        // ---- O^T = V^T·P^T per head; epilogue att = relu(O^T + R^T)^T ----
        short8 Va[2][2], Pb[2][2];
#pragma unroll
        for (int h = 0; h < 2; h++)
#pragma unroll
            for (int i = 0; i < 2; i++) {
                Va[h][i] = *(const short8*)&vtb[(h*32 + i*16 + c16)*40 + quad*8];
                Pb[h][i] = *(const short8*)&P[h*1280 + (i*16 + c16)*40 + quad*8];
            }
#pragma unroll
        for (int h = 0; h < 2; h++)
#pragma unroll
            for (int md = 0; md < 2; md++)
#pragma unroll
                for (int nq = 0; nq < 2; nq++) {
                    float4v O = __builtin_amdgcn_mfma_f32_16x16x32_bf16(
                        Va[h][md], Pb[h][nq], zero4, 0, 0, 0);
                    float4v r = Rf[h*2 + md][nq];
                    float4v o;
#pragma unroll
                    for (int reg = 0; reg < 4; reg++)
                        o[reg] = fmaxf(O[reg] + r[reg], 0.f);
                    // C[d][q]: lane q=c16, regs = 4 consecutive d -> b64
                    st4(&att[(nq*16 + c16)*72 + h*32 + md*16 + quad*4], o);
                }
        __syncthreads();
    }

    // ---- p1[b] = att_flat @ out_W[0:1664] ----
    float s = 0.f;
#pragma unroll
    for (int f = 0; f < NSP; f++)
        s = fmaf(b2f(att[f*72 + lane]), outW[f*EDIM + lane], s);
#pragma unroll
    for (int off = 32; off > 0; off >>= 1) s += __shfl_down(s, off);
    if (lane == 0) p1[b] = s;
}

// ---------------------------------------------------------------------------
// K3: fused DNN, MFMA bf16 (unchanged from round 3).
// ---------------------------------------------------------------------------
__global__ __launch_bounds__(256) void k_dnn(
    const float* __restrict__ X, const int* __restrict__ sidx,
    const float* __restrict__ emb, const unsigned short* __restrict__ pW1,
    const float* __restrict__ b1, const unsigned short* __restrict__ pW2,
    const float* __restrict__ b2, const float* __restrict__ outW,
    const float* __restrict__ logit0, const float* __restrict__ p1,
    float* __restrict__ out)
{
    __shared__ __align__(16) unsigned short smem[2560 + 16896 + 8704];  // 56320 B
    unsigned short* Abuf  = smem;                 // [64][40]
    unsigned short* h1buf = smem + 2560;          // [64][264]
    unsigned short* h2buf = smem + 2560 + 16896;  // [64][136]

    const int t    = threadIdx.x;
    const int lane = t & 63;
    const int w    = t >> 6;
    const int quad = lane >> 4;
    const int c16  = lane & 15;
    const int bM   = blockIdx.x * 64;

    float4v acc[4][4];
#pragma unroll
    for (int mt = 0; mt < 4; mt++)
#pragma unroll
        for (int nt = 0; nt < 4; nt++) acc[mt][nt] = (float4v){0.f, 0.f, 0.f, 0.f};

    const int kk = t & 31;   // k within chunk
    const int sr = t >> 5;   // sample base (0..7)

    for (int kc = 0; kc < KC1; kc++) {
        const int k   = kc * 32 + kk;
        const bool ok = k < DIN;
        const bool isd = k < NDN;
        const int km = k - NDN;
        const int f = km >> 6, e = km & 63;
#pragma unroll
        for (int r = 0; r < 8; r++) {
            int s = sr + r * 8;
            float v = 0.f;
            if (ok)
                v = isd ? X[(long)(bM + s) * XW + NSP + k]
                        : emb[((long)(f * VOC + sidx[(bM + s) * NSP + f])) * EDIM + e];
            Abuf[s * 40 + kk] = f2b(v);
        }
        __syncthreads();

        short8 Bf[4], Af[4];
#pragma unroll
        for (int nt = 0; nt < 4; nt++)
            Bf[nt] = *(const short8*)&pW1[((long)(kc * 16 + w * 4 + nt) * 64 + lane) * 8];
#pragma unroll
        for (int mt = 0; mt < 4; mt++)
            Af[mt] = *(const short8*)&Abuf[(mt * 16 + c16) * 40 + quad * 8];
#pragma unroll
        for (int mt = 0; mt < 4; mt++)
#pragma unroll
            for (int nt = 0; nt < 4; nt++)
                acc[mt][nt] = __builtin_amdgcn_mfma_f32_16x16x32_bf16(
                    Af[mt], Bf[nt], acc[mt][nt], 0, 0, 0);
        __syncthreads();
    }

#pragma unroll
    for (int nt = 0; nt < 4; nt++) {
        int n = w * 64 + nt * 16 + c16;
        float bias = b1[n];
#pragma unroll
        for (int mt = 0; mt < 4; mt++)
#pragma unroll
            for (int reg = 0; reg < 4; reg++)
                h1buf[(mt * 16 + quad * 4 + reg) * 264 + n] =
                    f2b(fmaxf(acc[mt][nt][reg] + bias, 0.f));
    }
    __syncthreads();

    float4v acc2[4][2];
#pragma unroll
    for (int mt = 0; mt < 4; mt++)
#pragma unroll
        for (int n2 = 0; n2 < 2; n2++) acc2[mt][n2] = (float4v){0.f, 0.f, 0.f, 0.f};
#pragma unroll
    for (int kc2 = 0; kc2 < 8; kc2++) {
        short8 Bf2[2], Af2[4];
#pragma unroll
        for (int n2 = 0; n2 < 2; n2++)
            Bf2[n2] = *(const short8*)&pW2[((kc2 * 8 + w * 2 + n2) * 64 + lane) * 8];
#pragma unroll
        for (int mt = 0; mt < 4; mt++)
            Af2[mt] = *(const short8*)&h1buf[(mt * 16 + c16) * 264 + kc2 * 32 + quad * 8];
#pragma unroll
        for (int mt = 0; mt < 4; mt++)
#pragma unroll
            for (int n2 = 0; n2 < 2; n2++)
                acc2[mt][n2] = __builtin_amdgcn_mfma_f32_16x16x32_bf16(
                    Af2[mt], Bf2[n2], acc2[mt][n2], 0, 0, 0);
    }
#pragma unroll
    for (int n2 = 0; n2 < 2; n2++) {
        int n = w * 32 + n2 * 16 + c16;
        float bias = b2[n];
#pragma unroll
        for (int mt = 0; mt < 4; mt++)
#pragma unroll
            for (int reg = 0; reg < 4; reg++)
                h2buf[(mt * 16 + quad * 4 + reg) * 136 + n] =
                    f2b(fmaxf(acc2[mt][n2][reg] + bias, 0.f));
    }
    __syncthreads();

    if (t < 64) {
        const float* ow2 = outW + NSP * EDIM;
        float s = 0.f;
#pragma unroll
        for (int c8 = 0; c8 < 16; c8++) {
            short8 h = *(const short8*)&h2buf[t * 136 + c8 * 8];
#pragma unroll
            for (int j = 0; j < 8; j++)
                s = fmaf(b2f((unsigned short)h[j]), ow2[c8 * 8 + j], s);
        }
        int bb = bM + t;
        float logit = logit0[bb] + p1[bb] + s;
        out[bb] = 1.f / (1.f + __expf(-logit));
    }
}

// ---------------------------------------------------------------------------
extern "C" void kernel_launch(void* const* d_in, const int* in_sizes, int n_in,
                              void* d_out, int out_size, void* d_ws, size_t ws_size,
                              hipStream_t stream) {
    const float* X    = (const float*)d_in[0];
    const int*   sidx = (const int*)d_in[1];
    const float* emb  = (const float*)d_in[2];
    const float* Wq   = (const float*)d_in[3];
    const float* Wk   = (const float*)d_in[4];
    const float* Wv   = (const float*)d_in[5];
    const float* Wres = (const float*)d_in[6];
    const float* W1   = (const float*)d_in[7];
    const float* b1   = (const float*)d_in[8];
    const float* W2   = (const float*)d_in[9];
    const float* b2   = (const float*)d_in[10];
    const float* outW = (const float*)d_in[11];
    const float* linW = (const float*)d_in[12];
    const float* linb = (const float*)d_in[13];
    float* out = (float*)d_out;

    float* logit0 = (float*)d_ws;                          // 32768 f
    float* p1     = logit0 + BATCH;                        // 32768 f
    unsigned short* pW  = (unsigned short*)(p1 + BATCH);   // 49152 bf16
    unsigned short* pW1 = pW + 49152;                      // 434176 bf16
    unsigned short* pW2 = pW1 + 434176;                    // 32768 bf16

    k_pack<<<2016, 256, 0, stream>>>(Wq, Wk, Wv, Wres, W1, W2, pW, pW1, pW2);
    k_lin<<<BATCH / 256, 256, 0, stream>>>(X, linW, linb, logit0);
    k_interact<<<BATCH, 64, 0, stream>>>(sidx, emb, pW, outW, p1);
    k_dnn<<<BATCH / 64, 256, 0, stream>>>(X, sidx, emb, pW1, b1, pW2, b2, outW,
                                          logit0, p1, out);
}

// Round 5
// 616.298 us; speedup vs baseline: 1.0429x; 1.0429x over previous
//
#include <hip/hip_runtime.h>
#include <math.h>

#define BATCH 32768
#define NSP 26
#define NDN 13
#define VOC 10000
#define EDIM 64
#define NLAY 3
#define HID1 256
#define HID2 128
#define DIN 1677          // 13 + 26*64
#define XW 39             // NSP + NDN
#define KC1 53            // GEMM1 K-chunks of 32 (K padded 1677 -> 1696)

typedef short short8 __attribute__((ext_vector_type(8)));
typedef float float4v __attribute__((ext_vector_type(4)));

__device__ __forceinline__ unsigned short f2b(float f) {
    unsigned u = __builtin_bit_cast(unsigned, f);
    u += 0x7FFFu + ((u >> 16) & 1u);          // RNE
    return (unsigned short)(u >> 16);
}
__device__ __forceinline__ float b2f(unsigned short h) {
    unsigned u = ((unsigned)h) << 16;
    return __builtin_bit_cast(float, u);
}
__device__ __forceinline__ unsigned pk2(float lo, float hi) {
    unsigned ul = __builtin_bit_cast(unsigned, lo);
    unsigned uh = __builtin_bit_cast(unsigned, hi);
    ul += 0x7FFFu + ((ul >> 16) & 1u);
    uh += 0x7FFFu + ((uh >> 16) & 1u);
    return (uh & 0xFFFF0000u) | (ul >> 16);
}
// pack a C-tile (4 f32 regs = rows quad*4+0..3, col c16) into 2 u32 bf16
__device__ __forceinline__ uint2 pkC(float4v c) {
    uint2 r; r.x = pk2(c[0], c[1]); r.y = pk2(c[2], c[3]); return r;
}
// store 4 C-regs (consecutive dest elements) as one ds_write_b64
__device__ __forceinline__ void st4(unsigned short* p, float4v v) {
    *(uint2*)p = pkC(v);
}

// ---------------------------------------------------------------------------
// C-layout -> A/B-fragment cross-quad shuffle.
// Input: packed-bf16 C-tiles t0 (covers k-rows 0..15) and t1 (k-rows 16..31),
// where source lane (c16, sq) holds rows sq*4+{0,1} in .x and sq*4+{2,3} in .y
// at column c16.  Output: this lane's frag element j = value at
// (k = quad*8+j, col = c16)  — exactly the MFMA A/B fragment mapping.
// s0 = c16 + 32*(quad&1), s1 = s0+16, hi = (quad>=2).
// ---------------------------------------------------------------------------
__device__ __forceinline__ short8 fragC(uint2 t0, uint2 t1, int s0, int s1, bool hi) {
    unsigned a0 = __shfl(t0.x, s0), a1 = __shfl(t0.y, s0);
    unsigned a2 = __shfl(t0.x, s1), a3 = __shfl(t0.y, s1);
    unsigned b0 = __shfl(t1.x, s0), b1 = __shfl(t1.y, s0);
    unsigned b2 = __shfl(t1.x, s1), b3 = __shfl(t1.y, s1);
    union { unsigned u[4]; short8 s; } r;
    r.u[0] = hi ? b0 : a0; r.u[1] = hi ? b1 : a1;
    r.u[2] = hi ? b2 : a2; r.u[3] = hi ? b3 : a3;
    return r.s;
}

// ---------------------------------------------------------------------------
// K0: pack all weights into MFMA fragment order (bf16).  (unchanged)
// ---------------------------------------------------------------------------
__global__ void k_pack(const float* __restrict__ Wq, const float* __restrict__ Wk,
                       const float* __restrict__ Wv, const float* __restrict__ Wr,
                       const float* __restrict__ W1, const float* __restrict__ W2,
                       unsigned short* __restrict__ pW,
                       unsigned short* __restrict__ pW1,
                       unsigned short* __restrict__ pW2) {
    int bid = blockIdx.x;
    if (bid < 192) {
        int tid = bid * 256 + threadIdx.x;   // 49152 total
        int j    = tid & 7;
        int lane = (tid >> 3) & 63;
        int kt   = (tid >> 9) & 1;
        int nt   = (tid >> 10) & 3;
        int m    = (tid >> 12) & 3;
        int l    = tid >> 14;
        const float* W = (m == 0) ? Wq : (m == 1) ? Wk : (m == 2) ? Wv : Wr;
        int k = kt * 32 + ((lane >> 4) << 3) + j;
        int n = nt * 16 + (lane & 15);
        pW[tid] = f2b(W[l * EDIM * EDIM + k * EDIM + n]);
    } else if (bid < 1888) {
        int tid = (bid - 192) * 256 + threadIdx.x;   // 434176 total
        int j    = tid & 7;
        int lane = (tid >> 3) & 63;
        int nt   = (tid >> 9) & 15;
        int kc   = tid >> 13;
        int k = kc * 32 + ((lane >> 4) << 3) + j;
        int n = nt * 16 + (lane & 15);
        pW1[tid] = (k < DIN) ? f2b(W1[(long)k * HID1 + n]) : (unsigned short)0;
    } else {
        int tid = (bid - 1888) * 256 + threadIdx.x;  // 32768 total
        int j    = tid & 7;
        int lane = (tid >> 3) & 63;
        int nt   = (tid >> 9) & 7;
        int kc   = tid >> 12;
        int k = kc * 32 + ((lane >> 4) << 3) + j;
        int n = nt * 16 + (lane & 15);
        pW2[tid] = f2b(W2[(long)k * HID2 + n]);
    }
}

// ---------------------------------------------------------------------------
// K1: logit0[b] = relu(X[b,:] @ lin_W + lin_b)
// ---------------------------------------------------------------------------
__global__ void k_lin(const float* __restrict__ X, const float* __restrict__ lw,
                      const float* __restrict__ lb, float* __restrict__ logit0) {
    int b = blockIdx.x * 256 + threadIdx.x;
    float s = lb[0];
    const float* xr = X + (long)b * XW;
#pragma unroll
    for (int i = 0; i < XW; i++) s = fmaf(xr[i], lw[i], s);
    logit0[b] = fmaxf(s, 0.f);
}

// ---------------------------------------------------------------------------
// K2: fused 3-layer AutoInt, MFMA bf16, register-resident dataflow.
// One wave = one sample.  LDS only for att (gather + inter-layer) and Q^T;
// K^T, V, R^T, S and P live in registers; C-layout -> next-frag conversion
// via fragC (cross-quad shuffles); softmax fully in-register (per-lane 8 keys
// + shfl_xor(16/32) reduction over quads; keys>=26 statically masked).
// LDS 9216 B/wave; __launch_bounds__(64,4) targets <=128 VGPR (16 waves/CU).
// Pad containment: att pad rows are garbage after layer 1, but pad KEYS are
// masked before exp (P pad-key = 0 kills V-pad cols) and p1 reads rows <26.
// ---------------------------------------------------------------------------
__global__ __launch_bounds__(64, 4) void k_interact(
    const int* __restrict__ sidx, const float* __restrict__ emb,
    const unsigned short* __restrict__ pW, const float* __restrict__ outW,
    float* __restrict__ p1)
{
    __shared__ __align__(16) unsigned short smem[32*72*2];   // 9216 B
    unsigned short* att = smem;            // [32 q][72]  row-major [q][e]
    unsigned short* qb  = smem + 32*72;    // [32 q][72]  row-major [q][d]

    const int lane = threadIdx.x;
    const int b    = blockIdx.x;
    const int quad = lane >> 4;
    const int c16  = lane & 15;
    const int s0   = c16 + 32*(quad & 1);  // fragC source lanes (fixed per lane)
    const int s1   = s0 + 16;
    const bool hi  = quad >= 2;
    const float4v zero4 = {0.f, 0.f, 0.f, 0.f};

    // gather embeddings -> att (bf16), coalesced over lane=e
#pragma unroll
    for (int f = 0; f < NSP; f++) {
        int idx = sidx[b * NSP + f];
        att[f * 72 + lane] = f2b(emb[((long)(f * VOC + idx)) * EDIM + lane]);
    }
#pragma unroll
    for (int r = NSP; r < 32; r++) att[r * 72 + lane] = 0;   // zero pad rows
    __syncthreads();

    for (int l = 0; l < NLAY; l++) {
        // att frags (A-of-att == B-of-att^T, same data)
        short8 Fatt[2][2];
#pragma unroll
        for (int qt = 0; qt < 2; qt++)
#pragma unroll
            for (int kt = 0; kt < 2; kt++)
                Fatt[qt][kt] = *(const short8*)&att[(qt*16 + c16)*72 + kt*32 + quad*8];

        const unsigned short* wl = pW + l * 16384;
        uint2 kpk[4][2];   // K^T C-tiles [dt][keyt]  (lane=key, regs=d)
        uint2 vpk[2][4];   // V   C-tiles [keyt][dt]  (lane=d,   regs=key)
        uint2 rpk[4][2];   // R^T C-tiles [dt][qt]    (lane=q,   regs=d)

        // ---- projections: m = 0:Q^T 1:K^T 2:V 3:R^T ----
#pragma unroll
        for (int m = 0; m < 4; m++) {
            short8 Wf[4][2];
#pragma unroll
            for (int nt = 0; nt < 4; nt++)
#pragma unroll
                for (int kt = 0; kt < 2; kt++)
                    Wf[nt][kt] = *(const short8*)&wl[(m*8 + nt*2 + kt)*512 + lane*8];

            if (m == 2) {
#pragma unroll
                for (int qt = 0; qt < 2; qt++)
#pragma unroll
                    for (int dt = 0; dt < 4; dt++) {
                        float4v acc = __builtin_amdgcn_mfma_f32_16x16x32_bf16(
                            Fatt[qt][0], Wf[dt][0], zero4, 0, 0, 0);
                        acc = __builtin_amdgcn_mfma_f32_16x16x32_bf16(
                            Fatt[qt][1], Wf[dt][1], acc, 0, 0, 0);
                        vpk[qt][dt] = pkC(acc);
                    }
            } else {
#pragma unroll
                for (int dt = 0; dt < 4; dt++)
#pragma unroll
                    for (int qt = 0; qt < 2; qt++) {
                        float4v acc = __builtin_amdgcn_mfma_f32_16x16x32_bf16(
                            Wf[dt][0], Fatt[qt][0], zero4, 0, 0, 0);
                        acc = __builtin_amdgcn_mfma_f32_16x16x32_bf16(
                            Wf[dt][1], Fatt[qt][1], acc, 0, 0, 0);
                        if (m == 0)
                            st4(&qb[(qt*16 + c16)*72 + dt*16 + quad*4], acc);
                        else if (m == 1)
                            kpk[dt][qt] = pkC(acc);
                        else
                            rpk[dt][qt] = pkC(acc);
                    }
            }
        }
        __syncthreads();   // qb ready

        // Q^T B-frags from LDS; K A-frags via fragC
        short8 Qb[2][2], Ka[2][2];
#pragma unroll
        for (int h = 0; h < 2; h++)
#pragma unroll
            for (int i = 0; i < 2; i++) {
                Qb[h][i] = *(const short8*)&qb[(i*16 + c16)*72 + h*32 + quad*8];
                Ka[h][i] = fragC(kpk[h*2][i], kpk[h*2+1][i], s0, s1, hi);
            }

        // ---- S^T = K.Q^T, in-register softmax, pack P ----
        uint2 Ppk[2][2][2];     // [h][mk(keyt)][nq]
#pragma unroll
        for (int h = 0; h < 2; h++)
#pragma unroll
            for (int nq = 0; nq < 2; nq++) {
                float4v S0 = __builtin_amdgcn_mfma_f32_16x16x32_bf16(
                    Ka[h][0], Qb[h][nq], zero4, 0, 0, 0);
                float4v S1 = __builtin_amdgcn_mfma_f32_16x16x32_bf16(
                    Ka[h][1], Qb[h][nq], zero4, 0, 0, 0);
                float sv[8];
#pragma unroll
                for (int r = 0; r < 4; r++) {
                    sv[r]     = S0[r];
                    sv[4 + r] = (quad*4 + r >= 10) ? -1e30f : S1[r];  // keys>=26
                }
                float mx = sv[0];
#pragma unroll
                for (int j = 1; j < 8; j++) mx = fmaxf(mx, sv[j]);
                mx = fmaxf(mx, __shfl_xor(mx, 16));
                mx = fmaxf(mx, __shfl_xor(mx, 32));
                float e[8], sum = 0.f;
#pragma unroll
                for (int j = 0; j < 8; j++) {
                    e[j] = (j >= 4 && quad*4 + (j-4) >= 10) ? 0.f : __expf(sv[j] - mx);
                    sum += e[j];
                }
                sum += __shfl_xor(sum, 16);
                sum += __shfl_xor(sum, 32);
                float inv = 1.f / sum;
                Ppk[h][0][nq].x = pk2(e[0]*inv, e[1]*inv);
                Ppk[h][0][nq].y = pk2(e[2]*inv, e[3]*inv);
                Ppk[h][1][nq].x = pk2(e[4]*inv, e[5]*inv);
                Ppk[h][1][nq].y = pk2(e[6]*inv, e[7]*inv);
            }

        // ---- O^T = V^T.P^T + R^T, relu, -> att ----
#pragma unroll
        for (int h = 0; h < 2; h++) {
            short8 Va[2], Pb[2];
#pragma unroll
            for (int i = 0; i < 2; i++) {
                Va[i] = fragC(vpk[0][h*2+i], vpk[1][h*2+i], s0, s1, hi);
                Pb[i] = fragC(Ppk[h][0][i],  Ppk[h][1][i],  s0, s1, hi);
            }
#pragma unroll
            for (int md = 0; md < 2; md++)
#pragma unroll
                for (int nq = 0; nq < 2; nq++) {
                    float4v O = __builtin_amdgcn_mfma_f32_16x16x32_bf16(
                        Va[md], Pb[nq], zero4, 0, 0, 0);
                    int dt = h*2 + md;
                    uint2 rp = rpk[dt][nq];
                    float4v o;
                    o[0] = fmaxf(O[0] + b2f((unsigned short)(rp.x & 0xFFFF)), 0.f);
                    o[1] = fmaxf(O[1] + b2f((unsigned short)(rp.x >> 16)),   0.f);
                    o[2] = fmaxf(O[2] + b2f((unsigned short)(rp.y & 0xFFFF)), 0.f);
                    o[3] = fmaxf(O[3] + b2f((unsigned short)(rp.y >> 16)),   0.f);
                    st4(&att[(nq*16 + c16)*72 + dt*16 + quad*4], o);
                }
        }
        __syncthreads();
    }

    // ---- p1[b] = att_flat @ out_W[0:1664] (rows <26 only) ----
    float s = 0.f;
#pragma unroll
    for (int f = 0; f < NSP; f++)
        s = fmaf(b2f(att[f*72 + lane]), outW[f*EDIM + lane], s);
#pragma unroll
    for (int off = 32; off > 0; off >>= 1) s += __shfl_down(s, off);
    if (lane == 0) p1[b] = s;
}

// ---------------------------------------------------------------------------
// K3: fused DNN, MFMA bf16.  h2buf now aliases Abuf/h1buf (extra barrier
// after GEMM2 reads) -> LDS 38912 B -> 4 blocks/CU (was 2).
// ---------------------------------------------------------------------------
__global__ __launch_bounds__(256) void k_dnn(
    const float* __restrict__ X, const int* __restrict__ sidx,
    const float* __restrict__ emb, const unsigned short* __restrict__ pW1,
    const float* __restrict__ b1, const unsigned short* __restrict__ pW2,
    const float* __restrict__ b2, const float* __restrict__ outW,
    const float* __restrict__ logit0, const float* __restrict__ p1,
    float* __restrict__ out)
{
    __shared__ __align__(16) unsigned short smem[2560 + 16896];  // 38912 B
    unsigned short* Abuf  = smem;                 // [64][40]
    unsigned short* h1buf = smem + 2560;          // [64][264]
    unsigned short* h2buf = smem;                 // [64][136] alias (after barrier)

    const int t    = threadIdx.x;
    const int lane = t & 63;
    const int w    = t >> 6;
    const int quad = lane >> 4;
    const int c16  = lane & 15;
    const int bM   = blockIdx.x * 64;

    float4v acc[4][4];
#pragma unroll
    for (int mt = 0; mt < 4; mt++)
#pragma unroll
        for (int nt = 0; nt < 4; nt++) acc[mt][nt] = (float4v){0.f, 0.f, 0.f, 0.f};

    const int kk = t & 31;   // k within chunk
    const int sr = t >> 5;   // sample base (0..7)

    for (int kc = 0; kc < KC1; kc++) {
        const int k   = kc * 32 + kk;
        const bool ok = k < DIN;
        const bool isd = k < NDN;
        const int km = k - NDN;
        const int f = km >> 6, e = km & 63;
#pragma unroll
        for (int r = 0; r < 8; r++) {
            int s = sr + r * 8;
            float v = 0.f;
            if (ok)
                v = isd ? X[(long)(bM + s) * XW + NSP + k]
                        : emb[((long)(f * VOC + sidx[(bM + s) * NSP + f])) * EDIM + e];
            Abuf[s * 40 + kk] = f2b(v);
        }
        __syncthreads();

        short8 Bf[4], Af[4];
#pragma unroll
        for (int nt = 0; nt < 4; nt++)
            Bf[nt] = *(const short8*)&pW1[((long)(kc * 16 + w * 4 + nt) * 64 + lane) * 8];
#pragma unroll
        for (int mt = 0; mt < 4; mt++)
            Af[mt] = *(const short8*)&Abuf[(mt * 16 + c16) * 40 + quad * 8];
#pragma unroll
        for (int mt = 0; mt < 4; mt++)
#pragma unroll
            for (int nt = 0; nt < 4; nt++)
                acc[mt][nt] = __builtin_amdgcn_mfma_f32_16x16x32_bf16(
                    Af[mt], Bf[nt], acc[mt][nt], 0, 0, 0);
        __syncthreads();
    }

    // ---- h1 = relu(acc + b1) -> LDS bf16 ----
#pragma unroll
    for (int nt = 0; nt < 4; nt++) {
        int n = w * 64 + nt * 16 + c16;
        float bias = b1[n];
#pragma unroll
        for (int mt = 0; mt < 4; mt++)
#pragma unroll
            for (int reg = 0; reg < 4; reg++)
                h1buf[(mt * 16 + quad * 4 + reg) * 264 + n] =
                    f2b(fmaxf(acc[mt][nt][reg] + bias, 0.f));
    }
    __syncthreads();

    // ---- GEMM2: h2 = relu(h1 @ W2 + b2), wave w -> cols [w*32, w*32+32) ----
    float4v acc2[4][2];
#pragma unroll
    for (int mt = 0; mt < 4; mt++)
#pragma unroll
        for (int n2 = 0; n2 < 2; n2++) acc2[mt][n2] = (float4v){0.f, 0.f, 0.f, 0.f};
#pragma unroll
    for (int kc2 = 0; kc2 < 8; kc2++) {
        short8 Bf2[2], Af2[4];
#pragma unroll
        for (int n2 = 0; n2 < 2; n2++)
            Bf2[n2] = *(const short8*)&pW2[((kc2 * 8 + w * 2 + n2) * 64 + lane) * 8];
#pragma unroll
        for (int mt = 0; mt < 4; mt++)
            Af2[mt] = *(const short8*)&h1buf[(mt * 16 + c16) * 264 + kc2 * 32 + quad * 8];
#pragma unroll
        for (int mt = 0; mt < 4; mt++)
#pragma unroll
            for (int n2 = 0; n2 < 2; n2++)
                acc2[mt][n2] = __builtin_amdgcn_mfma_f32_16x16x32_bf16(
                    Af2[mt], Bf2[n2], acc2[mt][n2], 0, 0, 0);
    }
    __syncthreads();   // all waves done reading h1 before h2 aliases it

#pragma unroll
    for (int n2 = 0; n2 < 2; n2++) {
        int n = w * 32 + n2 * 16 + c16;
        float bias = b2[n];
#pragma unroll
        for (int mt = 0; mt < 4; mt++)
#pragma unroll
            for (int reg = 0; reg < 4; reg++)
                h2buf[(mt * 16 + quad * 4 + reg) * 136 + n] =
                    f2b(fmaxf(acc2[mt][n2][reg] + bias, 0.f));
    }
    __syncthreads();

    if (t < 64) {
        const float* ow2 = outW + NSP * EDIM;
        float s = 0.f;
#pragma unroll
        for (int c8 = 0; c8 < 16; c8++) {
            short8 h = *(const short8*)&h2buf[t * 136 + c8 * 8];
#pragma unroll
            for (int j = 0; j < 8; j++)
                s = fmaf(b2f((unsigned short)h[j]), ow2[c8 * 8 + j], s);
        }
        int bb = bM + t;
        float logit = logit0[bb] + p1[bb] + s;
        out[bb] = 1.f / (1.f + __expf(-logit));
    }
}

// ---------------------------------------------------------------------------
extern "C" void kernel_launch(void* const* d_in, const int* in_sizes, int n_in,
                              void* d_out, int out_size, void* d_ws, size_t ws_size,
                              hipStream_t stream) {
    const float* X    = (const float*)d_in[0];
    const int*   sidx = (const int*)d_in[1];
    const float* emb  = (const float*)d_in[2];
    const float* Wq   = (const float*)d_in[3];
    const float* Wk   = (const float*)d_in[4];
    const float* Wv   = (const float*)d_in[5];
    const float* Wres = (const float*)d_in[6];
    const float* W1   = (const float*)d_in[7];
    const float* b1   = (const float*)d_in[8];
    const float* W2   = (const float*)d_in[9];
    const float* b2   = (const float*)d_in[10];
    const float* outW = (const float*)d_in[11];
    const float* linW = (const float*)d_in[12];
    const float* linb = (const float*)d_in[13];
    float* out = (float*)d_out;

    float* logit0 = (float*)d_ws;                          // 32768 f
    float* p1     = logit0 + BATCH;                        // 32768 f
    unsigned short* pW  = (unsigned short*)(p1 + BATCH);   // 49152 bf16
    unsigned short* pW1 = pW + 49152;                      // 434176 bf16
    unsigned short* pW2 = pW1 + 434176;                    // 32768 bf16

    k_pack<<<2016, 256, 0, stream>>>(Wq, Wk, Wv, Wres, W1, W2, pW, pW1, pW2);
    k_lin<<<BATCH / 256, 256, 0, stream>>>(X, linW, linb, logit0);
    k_interact<<<BATCH, 64, 0, stream>>>(sidx, emb, pW, outW, p1);
    k_dnn<<<BATCH / 64, 256, 0, stream>>>(X, sidx, emb, pW1, b1, pW2, b2, outW,
                                          logit0, p1, out);
}

// Round 6
// 380.266 us; speedup vs baseline: 1.6902x; 1.6207x over previous
//
#include <hip/hip_runtime.h>
#include <math.h>

#define BATCH 32768
#define NSP 26
#define NDN 13
#define VOC 10000
#define EDIM 64
#define NLAY 3
#define HID1 256
#define HID2 128
#define XW 39             // NSP + NDN
#define KCH 27            // GEMM1 feature-chunks of 64: 26 emb features + 1 dense

typedef short short8 __attribute__((ext_vector_type(8)));
typedef float float4v __attribute__((ext_vector_type(4)));

__device__ __forceinline__ unsigned short f2b(float f) {
    unsigned u = __builtin_bit_cast(unsigned, f);
    u += 0x7FFFu + ((u >> 16) & 1u);          // RNE
    return (unsigned short)(u >> 16);
}
__device__ __forceinline__ float b2f(unsigned short h) {
    unsigned u = ((unsigned)h) << 16;
    return __builtin_bit_cast(float, u);
}
__device__ __forceinline__ unsigned pk2(float lo, float hi) {
    unsigned ul = __builtin_bit_cast(unsigned, lo);
    unsigned uh = __builtin_bit_cast(unsigned, hi);
    ul += 0x7FFFu + ((ul >> 16) & 1u);
    uh += 0x7FFFu + ((uh >> 16) & 1u);
    return (uh & 0xFFFF0000u) | (ul >> 16);
}
// pack a C-tile (4 f32 regs = rows quad*4+0..3, col c16) into 2 u32 bf16
__device__ __forceinline__ uint2 pkC(float4v c) {
    uint2 r; r.x = pk2(c[0], c[1]); r.y = pk2(c[2], c[3]); return r;
}
__device__ __forceinline__ void st4(unsigned short* p, float4v v) {
    *(uint2*)p = pkC(v);
}
// concat two packed C-tiles into one K=32 MFMA operand.  EXACT k-permutation
// trick: slots j=0..3 carry tile a (k=quad*4+j), slots 4..7 tile b
// (k=16+quad*4+(j-4)); using the same slot->k map for BOTH A and B operands
// leaves the dot product unchanged.  Zero data movement (register adjacency).
__device__ __forceinline__ short8 cat(uint2 a, uint2 b) {
    union { unsigned u[4]; short8 s; } r;
    r.u[0] = a.x; r.u[1] = a.y; r.u[2] = b.x; r.u[3] = b.y;
    return r.s;
}

// ---------------------------------------------------------------------------
// K0: pack all weights into MFMA fragment order (bf16).
//  bid <  192 : Wq/Wk/Wv/Wres -> pW  [l][m][nt4][kt2][lane][j8]  (unchanged)
//  192..1919  : W1 -> pW1 [c27][kt2][nt16][lane][j8], feature-chunk row order:
//               chunk c<26 covers W1 rows 13+c*64 .. 13+c*64+63 (emb feature c)
//               chunk 26: rows 0..12 (dense) then zero pad
//  1920..2047 : W2 -> pW2 [kc8][nt8][lane][j8]  (unchanged)
// ---------------------------------------------------------------------------
__global__ void k_pack(const float* __restrict__ Wq, const float* __restrict__ Wk,
                       const float* __restrict__ Wv, const float* __restrict__ Wr,
                       const float* __restrict__ W1, const float* __restrict__ W2,
                       unsigned short* __restrict__ pW,
                       unsigned short* __restrict__ pW1,
                       unsigned short* __restrict__ pW2) {
    int bid = blockIdx.x;
    if (bid < 192) {
        int tid = bid * 256 + threadIdx.x;   // 49152 total
        int j    = tid & 7;
        int lane = (tid >> 3) & 63;
        int kt   = (tid >> 9) & 1;
        int nt   = (tid >> 10) & 3;
        int m    = (tid >> 12) & 3;
        int l    = tid >> 14;
        const float* W = (m == 0) ? Wq : (m == 1) ? Wk : (m == 2) ? Wv : Wr;
        int k = kt * 32 + ((lane >> 4) << 3) + j;
        int n = nt * 16 + (lane & 15);
        pW[tid] = f2b(W[l * EDIM * EDIM + k * EDIM + n]);
    } else if (bid < 1920) {
        int tid = (bid - 192) * 256 + threadIdx.x;   // 442368 total
        int j    = tid & 7;
        int lane = (tid >> 3) & 63;
        int nt   = (tid >> 9) & 15;
        int rest = tid >> 13;                // c*2 + kt
        int kt = rest & 1, c = rest >> 1;
        int kl = kt * 32 + ((lane >> 4) << 3) + j;   // k within chunk (0..63)
        int n  = nt * 16 + (lane & 15);
        int row;
        if (c < NSP) row = 13 + c * 64 + kl;
        else         row = (kl < NDN) ? kl : -1;
        pW1[tid] = (row >= 0) ? f2b(W1[(long)row * HID1 + n]) : (unsigned short)0;
    } else {
        int tid = (bid - 1920) * 256 + threadIdx.x;  // 32768 total
        int j    = tid & 7;
        int lane = (tid >> 3) & 63;
        int nt   = (tid >> 9) & 7;
        int kc   = tid >> 12;
        int k = kc * 32 + ((lane >> 4) << 3) + j;
        int n = nt * 16 + (lane & 15);
        pW2[tid] = f2b(W2[(long)k * HID2 + n]);
    }
}

// ---------------------------------------------------------------------------
// K1: logit0[b] = relu(X[b,:] @ lin_W + lin_b)
// ---------------------------------------------------------------------------
__global__ void k_lin(const float* __restrict__ X, const float* __restrict__ lw,
                      const float* __restrict__ lb, float* __restrict__ logit0) {
    int b = blockIdx.x * 256 + threadIdx.x;
    float s = lb[0];
    const float* xr = X + (long)b * XW;
#pragma unroll
    for (int i = 0; i < XW; i++) s = fmaf(xr[i], lw[i], s);
    logit0[b] = fmaxf(s, 0.f);
}

// ---------------------------------------------------------------------------
// K2: fused 3-layer AutoInt, MFMA bf16, fully register-resident chain.
// One wave = one sample; LDS only holds att (4608 B).  Q^T/K^T/V/R^T/P are
// C-layout register tiles; the S and PV MFMAs consume them directly via the
// exact k-permutation concat (see cat()) — no shuffles, no LDS round trips.
//   S^T[mk][nq] = mfma32(cat(kpk[h2][mk],kpk[h2+1][mk]), cat(qpk...), 0)
//   O^T[md][nq] = mfma32(cat(vpk[0][dt],vpk[1][dt]), cat(Ppk...), 0)
// Softmax in-register (8 keys/lane + shfl_xor 16/32; keys>=26 masked).
// ---------------------------------------------------------------------------
__global__ __launch_bounds__(64, 3) void k_interact(
    const int* __restrict__ sidx, const float* __restrict__ emb,
    const unsigned short* __restrict__ pW, const float* __restrict__ outW,
    float* __restrict__ p1)
{
    __shared__ __align__(16) unsigned short att[32 * 72];   // 4608 B

    const int lane = threadIdx.x;
    const int b    = blockIdx.x;
    const int quad = lane >> 4;
    const int c16  = lane & 15;
    const float4v zero4 = {0.f, 0.f, 0.f, 0.f};

    // gather embeddings -> att (bf16), coalesced over lane=e
#pragma unroll
    for (int f = 0; f < NSP; f++) {
        int idx = sidx[b * NSP + f];
        att[f * 72 + lane] = f2b(emb[((long)(f * VOC + idx)) * EDIM + lane]);
    }
#pragma unroll
    for (int r = NSP; r < 32; r++) att[r * 72 + lane] = 0;   // zero pad rows
    __syncthreads();

    for (int l = 0; l < NLAY; l++) {
        short8 Fatt[2][2];
#pragma unroll
        for (int qt = 0; qt < 2; qt++)
#pragma unroll
            for (int kt = 0; kt < 2; kt++)
                Fatt[qt][kt] = *(const short8*)&att[(qt*16 + c16)*72 + kt*32 + quad*8];

        const unsigned short* wl = pW + l * 16384;
        uint2 qpk[4][2];   // Q^T tiles [dt][qt]   (lane=q,   regs=d)
        uint2 kpk[4][2];   // K^T tiles [dt][keyt] (lane=key, regs=d)
        uint2 vpk[2][4];   // V   tiles [keyt][dt] (lane=d,   regs=key)
        uint2 rpk[4][2];   // R^T tiles [dt][qt]   (lane=q,   regs=d)

        // ---- projections: m = 0:Q^T 1:K^T 2:V 3:R^T ----
#pragma unroll
        for (int m = 0; m < 4; m++) {
            short8 Wf[4][2];
#pragma unroll
            for (int nt = 0; nt < 4; nt++)
#pragma unroll
                for (int kt = 0; kt < 2; kt++)
                    Wf[nt][kt] = *(const short8*)&wl[(m*8 + nt*2 + kt)*512 + lane*8];

            if (m == 2) {
#pragma unroll
                for (int qt = 0; qt < 2; qt++)
#pragma unroll
                    for (int dt = 0; dt < 4; dt++) {
                        float4v acc = __builtin_amdgcn_mfma_f32_16x16x32_bf16(
                            Fatt[qt][0], Wf[dt][0], zero4, 0, 0, 0);
                        acc = __builtin_amdgcn_mfma_f32_16x16x32_bf16(
                            Fatt[qt][1], Wf[dt][1], acc, 0, 0, 0);
                        vpk[qt][dt] = pkC(acc);
                    }
            } else {
#pragma unroll
                for (int dt = 0; dt < 4; dt++)
#pragma unroll
                    for (int qt = 0; qt < 2; qt++) {
                        float4v acc = __builtin_amdgcn_mfma_f32_16x16x32_bf16(
                            Wf[dt][0], Fatt[qt][0], zero4, 0, 0, 0);
                        acc = __builtin_amdgcn_mfma_f32_16x16x32_bf16(
                            Wf[dt][1], Fatt[qt][1], acc, 0, 0, 0);
                        if (m == 0)      qpk[dt][qt] = pkC(acc);
                        else if (m == 1) kpk[dt][qt] = pkC(acc);
                        else             rpk[dt][qt] = pkC(acc);
                    }
            }
        }

        // ---- S^T = K.Q^T, in-register softmax, pack P ----
        uint2 Ppk[2][2][2];     // [h][keyt][nq]  (lane=q, regs=key)
#pragma unroll
        for (int h = 0; h < 2; h++)
#pragma unroll
            for (int nq = 0; nq < 2; nq++) {
                short8 Qc = cat(qpk[h*2][nq], qpk[h*2+1][nq]);
                float4v S0 = __builtin_amdgcn_mfma_f32_16x16x32_bf16(
                    cat(kpk[h*2][0], kpk[h*2+1][0]), Qc, zero4, 0, 0, 0);
                float4v S1 = __builtin_amdgcn_mfma_f32_16x16x32_bf16(
                    cat(kpk[h*2][1], kpk[h*2+1][1]), Qc, zero4, 0, 0, 0);
                float sv[8];
#pragma unroll
                for (int r = 0; r < 4; r++) {
                    sv[r]     = S0[r];
                    sv[4 + r] = (quad*4 + r >= 10) ? -1e30f : S1[r];  // keys>=26
                }
                float mx = sv[0];
#pragma unroll
                for (int j = 1; j < 8; j++) mx = fmaxf(mx, sv[j]);
                mx = fmaxf(mx, __shfl_xor(mx, 16));
                mx = fmaxf(mx, __shfl_xor(mx, 32));
                float e[8], sum = 0.f;
#pragma unroll
                for (int j = 0; j < 8; j++) {
                    e[j] = (j >= 4 && quad*4 + (j-4) >= 10) ? 0.f : __expf(sv[j] - mx);
                    sum += e[j];
                }
                sum += __shfl_xor(sum, 16);
                sum += __shfl_xor(sum, 32);
                float inv = 1.f / sum;
                Ppk[h][0][nq].x = pk2(e[0]*inv, e[1]*inv);
                Ppk[h][0][nq].y = pk2(e[2]*inv, e[3]*inv);
                Ppk[h][1][nq].x = pk2(e[4]*inv, e[5]*inv);
                Ppk[h][1][nq].y = pk2(e[6]*inv, e[7]*inv);
            }

        // ---- O^T = V^T.P^T + R^T, relu, -> att ----
#pragma unroll
        for (int h = 0; h < 2; h++)
#pragma unroll
            for (int md = 0; md < 2; md++) {
                int dt = h*2 + md;
                short8 Vc = cat(vpk[0][dt], vpk[1][dt]);
#pragma unroll
                for (int nq = 0; nq < 2; nq++) {
                    float4v O = __builtin_amdgcn_mfma_f32_16x16x32_bf16(
                        Vc, cat(Ppk[h][0][nq], Ppk[h][1][nq]), zero4, 0, 0, 0);
                    uint2 rp = rpk[dt][nq];
                    float4v o;
                    o[0] = fmaxf(O[0] + b2f((unsigned short)(rp.x & 0xFFFF)), 0.f);
                    o[1] = fmaxf(O[1] + b2f((unsigned short)(rp.x >> 16)),   0.f);
                    o[2] = fmaxf(O[2] + b2f((unsigned short)(rp.y & 0xFFFF)), 0.f);
                    o[3] = fmaxf(O[3] + b2f((unsigned short)(rp.y >> 16)),   0.f);
                    st4(&att[(nq*16 + c16)*72 + dt*16 + quad*4], o);
                }
            }
        __syncthreads();
    }

    // ---- p1[b] = att_flat @ out_W[0:1664] (rows <26 only) ----
    float s = 0.f;
#pragma unroll
    for (int f = 0; f < NSP; f++)
        s = fmaf(b2f(att[f*72 + lane]), outW[f*EDIM + lane], s);
#pragma unroll
    for (int off = 32; off > 0; off >>= 1) s += __shfl_down(s, off);
    if (lane == 0) p1[b] = s;
}

// ---------------------------------------------------------------------------
// K3: fused DNN, MFMA bf16.  GEMM1 K-loop = 27 feature-chunks of 64: each
// emb chunk stages whole 256B emb rows via coalesced float4 loads (no 4B
// scalar gather); dense cols live in the tail chunk.  pW1 row order matches.
// h1buf/h2buf overlap Abuf temporally -> LDS 33792 B -> 4 blocks/CU.
// ---------------------------------------------------------------------------
__global__ __launch_bounds__(256) void k_dnn(
    const float* __restrict__ X, const int* __restrict__ sidx,
    const float* __restrict__ emb, const unsigned short* __restrict__ pW1,
    const float* __restrict__ b1, const unsigned short* __restrict__ pW2,
    const float* __restrict__ b2, const float* __restrict__ outW,
    const float* __restrict__ logit0, const float* __restrict__ p1,
    float* __restrict__ out)
{
    __shared__ __align__(16) unsigned short smem[64 * 264];  // 33792 B
    unsigned short* Abuf  = smem;        // [64][72]  during GEMM1
    unsigned short* h1buf = smem;        // [64][264] after GEMM1 (Abuf dead)
    unsigned short* h2buf = smem;        // [64][136] after GEMM2 (barrier)

    const int t    = threadIdx.x;
    const int lane = t & 63;
    const int w    = t >> 6;
    const int quad = lane >> 4;
    const int c16  = lane & 15;
    const int bM   = blockIdx.x * 64;
    const int sr   = t >> 2;      // staging sample (0..63)
    const int part = t & 3;       // staging 16-element slice

    float4v acc[4][4];
#pragma unroll
    for (int mt = 0; mt < 4; mt++)
#pragma unroll
        for (int nt = 0; nt < 4; nt++) acc[mt][nt] = (float4v){0.f, 0.f, 0.f, 0.f};

    for (int c = 0; c < KCH; c++) {
        // ---- stage A chunk: 64 samples x 64 k (bf16) ----
        if (c < NSP) {
            int idx = sidx[(bM + sr) * NSP + c];
            const float4* src = (const float4*)(emb + ((long)(c * VOC + idx)) * EDIM + part * 16);
            float4 a = src[0], bb = src[1], cc = src[2], dd = src[3];
            uint4 w0 = { pk2(a.x,a.y),  pk2(a.z,a.w),  pk2(bb.x,bb.y), pk2(bb.z,bb.w) };
            uint4 w1 = { pk2(cc.x,cc.y), pk2(cc.z,cc.w), pk2(dd.x,dd.y), pk2(dd.z,dd.w) };
            *(uint4*)&Abuf[sr * 72 + part * 16]     = w0;
            *(uint4*)&Abuf[sr * 72 + part * 16 + 8] = w1;
        } else {
            unsigned short v[16];
#pragma unroll
            for (int i = 0; i < 16; i++) {
                int j = part * 16 + i;
                v[i] = (j < NDN) ? f2b(X[(long)(bM + sr) * XW + NSP + j])
                                 : (unsigned short)0;
            }
            *(uint4*)&Abuf[sr * 72 + part * 16]     = *(uint4*)&v[0];
            *(uint4*)&Abuf[sr * 72 + part * 16 + 8] = *(uint4*)&v[8];
        }
        __syncthreads();

#pragma unroll
        for (int kt = 0; kt < 2; kt++) {
            short8 Bf[4], Af[4];
#pragma unroll
            for (int nt = 0; nt < 4; nt++)
                Bf[nt] = *(const short8*)&pW1[((long)((c*2 + kt)*16 + w*4 + nt) * 64 + lane) * 8];
#pragma unroll
            for (int mt = 0; mt < 4; mt++)
                Af[mt] = *(const short8*)&Abuf[(mt*16 + c16)*72 + kt*32 + quad*8];
#pragma unroll
            for (int mt = 0; mt < 4; mt++)
#pragma unroll
                for (int nt = 0; nt < 4; nt++)
                    acc[mt][nt] = __builtin_amdgcn_mfma_f32_16x16x32_bf16(
                        Af[mt], Bf[nt], acc[mt][nt], 0, 0, 0);
        }
        __syncthreads();
    }

    // ---- h1 = relu(acc + b1) -> LDS bf16 (overlaps dead Abuf) ----
#pragma unroll
    for (int nt = 0; nt < 4; nt++) {
        int n = w * 64 + nt * 16 + c16;
        float bias = b1[n];
#pragma unroll
        for (int mt = 0; mt < 4; mt++)
#pragma unroll
            for (int reg = 0; reg < 4; reg++)
                h1buf[(mt * 16 + quad * 4 + reg) * 264 + n] =
                    f2b(fmaxf(acc[mt][nt][reg] + bias, 0.f));
    }
    __syncthreads();

    // ---- GEMM2: h2 = relu(h1 @ W2 + b2), wave w -> cols [w*32, w*32+32) ----
    float4v acc2[4][2];
#pragma unroll
    for (int mt = 0; mt < 4; mt++)
#pragma unroll
        for (int n2 = 0; n2 < 2; n2++) acc2[mt][n2] = (float4v){0.f, 0.f, 0.f, 0.f};
#pragma unroll
    for (int kc2 = 0; kc2 < 8; kc2++) {
        short8 Bf2[2], Af2[4];
#pragma unroll
        for (int n2 = 0; n2 < 2; n2++)
            Bf2[n2] = *(const short8*)&pW2[((kc2 * 8 + w * 2 + n2) * 64 + lane) * 8];
#pragma unroll
        for (int mt = 0; mt < 4; mt++)
            Af2[mt] = *(const short8*)&h1buf[(mt * 16 + c16) * 264 + kc2 * 32 + quad * 8];
#pragma unroll
        for (int mt = 0; mt < 4; mt++)
#pragma unroll
            for (int n2 = 0; n2 < 2; n2++)
                acc2[mt][n2] = __builtin_amdgcn_mfma_f32_16x16x32_bf16(
                    Af2[mt], Bf2[n2], acc2[mt][n2], 0, 0, 0);
    }
    __syncthreads();   // all waves done reading h1 before h2 aliases it

#pragma unroll
    for (int n2 = 0; n2 < 2; n2++) {
        int n = w * 32 + n2 * 16 + c16;
        float bias = b2[n];
#pragma unroll
        for (int mt = 0; mt < 4; mt++)
#pragma unroll
            for (int reg = 0; reg < 4; reg++)
                h2buf[(mt * 16 + quad * 4 + reg) * 136 + n] =
                    f2b(fmaxf(acc2[mt][n2][reg] + bias, 0.f));
    }
    __syncthreads();

    // ---- p2 + final sigmoid ----
    if (t < 64) {
        const float* ow2 = outW + NSP * EDIM;
        float s = 0.f;
#pragma unroll
        for (int c8 = 0; c8 < 16; c8++) {
            short8 h = *(const short8*)&h2buf[t * 136 + c8 * 8];
#pragma unroll
            for (int j = 0; j < 8; j++)
                s = fmaf(b2f((unsigned short)h[j]), ow2[c8 * 8 + j], s);
        }
        int bb = bM + t;
        float logit = logit0[bb] + p1[bb] + s;
        out[bb] = 1.f / (1.f + __expf(-logit));
    }
}

// ---------------------------------------------------------------------------
extern "C" void kernel_launch(void* const* d_in, const int* in_sizes, int n_in,
                              void* d_out, int out_size, void* d_ws, size_t ws_size,
                              hipStream_t stream) {
    const float* X    = (const float*)d_in[0];
    const int*   sidx = (const int*)d_in[1];
    const float* emb  = (const float*)d_in[2];
    const float* Wq   = (const float*)d_in[3];
    const float* Wk   = (const float*)d_in[4];
    const float* Wv   = (const float*)d_in[5];
    const float* Wres = (const float*)d_in[6];
    const float* W1   = (const float*)d_in[7];
    const float* b1   = (const float*)d_in[8];
    const float* W2   = (const float*)d_in[9];
    const float* b2   = (const float*)d_in[10];
    const float* outW = (const float*)d_in[11];
    const float* linW = (const float*)d_in[12];
    const float* linb = (const float*)d_in[13];
    float* out = (float*)d_out;

    float* logit0 = (float*)d_ws;                          // 32768 f
    float* p1     = logit0 + BATCH;                        // 32768 f
    unsigned short* pW  = (unsigned short*)(p1 + BATCH);   // 49152 bf16
    unsigned short* pW1 = pW + 49152;                      // 442368 bf16
    unsigned short* pW2 = pW1 + 442368;                    // 32768 bf16

    k_pack<<<2048, 256, 0, stream>>>(Wq, Wk, Wv, Wres, W1, W2, pW, pW1, pW2);
    k_lin<<<BATCH / 256, 256, 0, stream>>>(X, linW, linb, logit0);
    k_interact<<<BATCH, 64, 0, stream>>>(sidx, emb, pW, outW, p1);
    k_dnn<<<BATCH / 64, 256, 0, stream>>>(X, sidx, emb, pW1, b1, pW2, b2, outW,
                                          logit0, p1, out);
}